// Round 14
// baseline (299.496 us; speedup 1.0000x reference)
//
#include <hip/hip_runtime.h>

static constexpr int F = 128;
static constexpr int N_RBF = 20;
static constexpr int N_ATOMS = 8000;
static constexpr int NP = 8064;          // padded to 128
static constexpr int N_EDGES = 160000;
static constexpr int N_MOLS = 100;
static constexpr float CUTOFF = 5.0f;
static constexpr size_t NFC = (size_t)NP * F;
static constexpr int REC = 28;           // j, ev, ux,uy,uz, rbf[20], pad[3]
static constexpr int NPHI_BLK = NP / 32;                 // 252
static constexpr int NBUILD_BLK = (N_EDGES + 511) / 512; // 313 (512 threads/block)
#define PIF 3.14159265358979323846f

typedef __attribute__((ext_vector_type(8))) short bf16x8;
typedef __attribute__((ext_vector_type(4))) float f32x4;
typedef unsigned short ushort_t;
typedef unsigned int uint_t;

__device__ __forceinline__ float silu_f(float x) { return x / (1.f + __expf(-x)); }

__device__ __forceinline__ ushort_t f2bf(float x) {   // round-to-nearest-even
    union { float f; uint_t u; } v; v.f = x;
    uint_t r = v.u + 0x7fffu + ((v.u >> 16) & 1u);
    return (ushort_t)(r >> 16);
}
__device__ __forceinline__ float bf2f(ushort_t h) {
    union { uint_t u; float f; } v; v.u = ((uint_t)h) << 16; return v.f;
}

// Session lessons:
//  - r4: cooperative launch silently fails under graph capture -> zeros.
//  - r5: fusing edge-gather into the MFMA kernel: 3x slower (latency, no TLP).
//  - r6: phi/v/s inter-layer activations MUST stay f32 (bf16 phi -> 49% output error).
//  - r7/r8/r9/r10: prefetch depth / pad / direct-B / small tiles all regressed.
//  - r12: r3 + build/phi0 merge = 318us. r13: updphi -> 512thr/8 waves (2 waves/SIMD
//    hide latency; per-wave cols halved; identical math order) = 298us.
//  - THIS ROUND: same verified 8-wave port applied to the phi0 half of build_phi0.

// ---------------- pass 1: distance + envelope + live-edge histogram ----------------
__global__ __launch_bounds__(256) void count_kernel(
    const float* __restrict__ xyz, const int* __restrict__ nbrs,
    float* __restrict__ envb, int* __restrict__ cnt)
{
    int e = blockIdx.x * 256 + threadIdx.x;
    if (e >= N_EDGES) return;
    int i0 = nbrs[2*e+0], i1 = nbrs[2*e+1];
    float dx = xyz[3*i1+0] - xyz[3*i0+0];
    float dy = xyz[3*i1+1] - xyz[3*i0+1];
    float dz = xyz[3*i1+2] - xyz[3*i0+2];
    float d  = sqrtf(dx*dx + dy*dy + dz*dz);
    float ev = (d <= CUTOFF) ? 0.5f*(cosf(PIF*d/CUTOFF) + 1.f) : 0.f;
    envb[e] = ev;
    if (ev > 0.f) atomicAdd(&cnt[i0], 1);
}

// ---------------- exclusive scan of 8000 counters (single block) + zero out ----------------
__global__ __launch_bounds__(1024) void scan_kernel(
    const int* __restrict__ cnt, int* __restrict__ offsets, float* __restrict__ out)
{
    __shared__ int sums[1024];
    int tid = threadIdx.x;
    if (tid < N_MOLS) out[tid] = 0.f;
    int base = tid * 8;
    int local[8]; int s = 0;
    #pragma unroll
    for (int i = 0; i < 8; ++i) {
        int idx = base + i;
        local[i] = (idx < N_ATOMS) ? cnt[idx] : 0;
        s += local[i];
    }
    sums[tid] = s;
    __syncthreads();
    for (int d = 1; d < 1024; d <<= 1) {
        int v = (tid >= d) ? sums[tid - d] : 0;
        __syncthreads();
        sums[tid] += v;
        __syncthreads();
    }
    int ex = (tid == 0) ? 0 : sums[tid - 1];
    #pragma unroll
    for (int i = 0; i < 8; ++i) {
        int idx = base + i;
        if (idx < N_ATOMS) { offsets[idx] = ex; ex += local[i]; }
    }
}

// ---------------- fused prep: embed + weight transpose/split + zero cnt/cursor ----------------
static constexpr int WPREP_W = 557056;
static constexpr int WPREP_TOTAL = 557184;
static constexpr int NATF = N_ATOMS * F;
static constexpr int PREP_TOTAL = NATF + WPREP_TOTAL + 2 * N_ATOMS;
__global__ __launch_bounds__(256) void prep_kernel(
    const float* __restrict__ emb, const int* __restrict__ z, float* __restrict__ s,
    const float* __restrict__ msg_w1, const float* __restrict__ msg_w2,
    const float* __restrict__ upd_u,  const float* __restrict__ upd_v,
    const float* __restrict__ upd_w1, const float* __restrict__ upd_w2,
    const float* __restrict__ ro_w1,  const float* __restrict__ ro_b1,
    ushort_t* __restrict__ dhi, ushort_t* __restrict__ dlo,
    float* __restrict__ robias, int* __restrict__ cntz)
{
    int gidx = blockIdx.x * 256 + threadIdx.x;
    if (gidx < NATF) {                          // s = emb_table[z]
        int n = gidx >> 7, f = gidx & 127;
        s[gidx] = emb[z[n]*F + f];
        return;
    }
    int idx = gidx - NATF;
    if (idx >= WPREP_TOTAL) {                   // zero cnt + cursor (adjacent)
        cntz[idx - WPREP_TOTAL] = 0;
        return;
    }
    if (idx >= WPREP_W) {
        int l = idx - WPREP_W;
        robias[l] = (l < 64) ? ro_b1[l] : 0.f;
        return;
    }
    float val;
    if (idx < 540672) {
        const float* src; int K, N, rem;
        if (idx < 49152)       { int l = idx;          int c = l / 16384; rem = l % 16384; K = 128; N = 128; src = msg_w1 + c * 16384; }
        else if (idx < 196608) { int l = idx - 49152;  int c = l / 49152; rem = l % 49152; K = 128; N = 384; src = msg_w2 + c * 49152; }
        else if (idx < 294912) { int l = idx - 196608; int c = l / 32768; rem = l % 32768; K = 128; N = 128;
                                 if (rem < 16384) src = upd_u + c * 16384;
                                 else { src = upd_v + c * 16384; rem -= 16384; } }
        else if (idx < 393216) { int l = idx - 294912; int c = l / 32768; rem = l % 32768; K = 256; N = 128; src = upd_w1 + c * 32768; }
        else                   { int l = idx - 393216; int c = l / 49152; rem = l % 49152; K = 128; N = 384; src = upd_w2 + c * 49152; }
        int n = rem / K, k = rem % K;
        val = src[k * N + n];
    } else {
        int l = idx - 540672;             // ro_w1 pad: [n][k], n>=64 -> 0
        int n = l >> 7, k = l & 127;
        val = (n < 64) ? ro_w1[k * 64 + n] : 0.f;
    }
    ushort_t h = f2bf(val);
    dhi[idx] = h;
    dlo[idx] = f2bf(val - bf2f(h));
}

// ---------------- merged (512 thr): phi0 MLP 8-wave (blocks [0,252)) + build (blocks [252,565)) ----------------
__global__ __launch_bounds__(512) void build_phi0_kernel(
    const float* __restrict__ xyz, const int* __restrict__ nbrs,
    const float* __restrict__ envb, const int* __restrict__ offsets,
    int* __restrict__ cursor, float* __restrict__ rec,
    const float* __restrict__ sbuf,
    const ushort_t* __restrict__ W1h, const ushort_t* __restrict__ W1l,
    const float* __restrict__ b1,
    const ushort_t* __restrict__ W2h, const ushort_t* __restrict__ W2l,
    const float* __restrict__ b2,
    float* __restrict__ C)
{
    if (blockIdx.x >= NPHI_BLK) {
        // ---------- build body (512 edges/block) ----------
        int e = (blockIdx.x - NPHI_BLK) * 512 + threadIdx.x;
        if (e >= N_EDGES) return;
        float ev = envb[e];
        if (ev <= 0.f) return;
        int i0 = nbrs[2*e+0], i1 = nbrs[2*e+1];
        float dx = xyz[3*i1+0] - xyz[3*i0+0];
        float dy = xyz[3*i1+1] - xyz[3*i0+1];
        float dz = xyz[3*i1+2] - xyz[3*i0+2];
        float d  = sqrtf(dx*dx + dy*dy + dz*dz);
        float inv = 1.f / d;
        int pos = offsets[i0] + atomicAdd(&cursor[i0], 1);
        float* r = rec + (size_t)pos * REC;
        r[0] = __int_as_float(i1);
        r[1] = ev;
        r[2] = dx*inv; r[3] = dy*inv; r[4] = dz*inv;
        float base = PIF*d/CUTOFF;
        float sc = inv * ev;   // fold env into rbf (w_s = (rbf*env)@W + b*env)
        #pragma unroll
        for (int k = 0; k < N_RBF; ++k)
            r[5 + k] = sinf((float)(k+1)*base) * sc;
        return;
    }

    // ---------- phi0 body: 8 waves, 16 cols/wave (verified r13 mapping) ----------
    __shared__ __align__(16) ushort_t Ah[2][32 * 40], Al[2][32 * 40];
    __shared__ __align__(16) ushort_t Bh[2][128 * 40], Bl[2][128 * 40];
    __shared__ __align__(16) ushort_t Hh[32 * 136], Hl[32 * 136];
    const int tid = threadIdx.x;
    const int wave = tid >> 6, lane = tid & 63;        // wave 0..7
    const int row_l = lane & 15, quad = lane >> 4;
    const int wn16 = wave * 16;
    const int m0 = blockIdx.x * 32;
    const int lrA = tid >> 3, ksA = (tid & 7) * 4;     // A-stage: tid<256 only
    const int lrB4 = tid >> 2, ksB4 = (tid & 3) * 8;   // B-stage: 128 rows x 32k, 1 uint4/thr

    float4 rx;
    uint4 b_h0, b_l0;

    auto loadB1 = [&](int k0) {
        b_h0 = *(const uint4*)&W1h[(size_t)lrB4 * 128 + k0 + ksB4];
        b_l0 = *(const uint4*)&W1l[(size_t)lrB4 * 128 + k0 + ksB4];
    };
    auto loadB2 = [&](int it2) {
        int ct = it2 >> 2, k0 = (it2 & 3) * 32;
        b_h0 = *(const uint4*)&W2h[(size_t)(ct * 128 + lrB4) * 128 + k0 + ksB4];
        b_l0 = *(const uint4*)&W2l[(size_t)(ct * 128 + lrB4) * 128 + k0 + ksB4];
    };
    auto writeA = [&](int buf) {                       // tid < 256 only
        float e[4] = {rx.x, rx.y, rx.z, rx.w};
        ushort_t ph[4], pl[4];
        #pragma unroll
        for (int t = 0; t < 4; ++t) {
            ushort_t h = f2bf(e[t]);
            ph[t] = h; pl[t] = f2bf(e[t] - bf2f(h));
        }
        *(uint2*)&Ah[buf][lrA * 40 + ksA] = *(uint2*)ph;
        *(uint2*)&Al[buf][lrA * 40 + ksA] = *(uint2*)pl;
    };
    auto writeB = [&](int buf) {
        *(uint4*)&Bh[buf][lrB4 * 40 + ksB4] = b_h0;
        *(uint4*)&Bl[buf][lrB4 * 40 + ksB4] = b_l0;
    };

    f32x4 acc[2];
    #pragma unroll
    for (int i = 0; i < 2; ++i)
        #pragma unroll
        for (int r = 0; r < 4; ++r) acc[i][r] = 0.f;

    if (tid < 256) rx = *(const float4*)&sbuf[(size_t)(m0 + lrA) * 128 + ksA];
    loadB1(0);
    if (tid < 256) writeA(0);
    writeB(0);
    __syncthreads();
    #pragma unroll
    for (int it = 0; it < 4; ++it) {
        const int k0n = (it + 1) * 32;
        if (it + 1 < 4) {
            if (tid < 256) rx = *(const float4*)&sbuf[(size_t)(m0 + lrA) * 128 + k0n + ksA];
            loadB1(k0n);
        }
        bf16x8 ahf[2], alf[2], bhf, blf;
        #pragma unroll
        for (int i = 0; i < 2; ++i) {
            int ar = (i * 16 + row_l) * 40 + quad * 8;
            ahf[i] = *(const bf16x8*)&Ah[it & 1][ar];
            alf[i] = *(const bf16x8*)&Al[it & 1][ar];
        }
        {
            int br = (wn16 + row_l) * 40 + quad * 8;
            bhf = *(const bf16x8*)&Bh[it & 1][br];
            blf = *(const bf16x8*)&Bl[it & 1][br];
        }
        #pragma unroll
        for (int i = 0; i < 2; ++i) {
            acc[i] = __builtin_amdgcn_mfma_f32_16x16x32_bf16(ahf[i], bhf, acc[i], 0, 0, 0);
            acc[i] = __builtin_amdgcn_mfma_f32_16x16x32_bf16(ahf[i], blf, acc[i], 0, 0, 0);
            acc[i] = __builtin_amdgcn_mfma_f32_16x16x32_bf16(alf[i], bhf, acc[i], 0, 0, 0);
        }
        if (it + 1 < 4) { if (tid < 256) writeA((it + 1) & 1); writeB((it + 1) & 1); }
        __syncthreads();
    }
    {
        int col = wn16 + row_l;
        float bval = b1[col];
        #pragma unroll
        for (int i = 0; i < 2; ++i)
            #pragma unroll
            for (int r = 0; r < 4; ++r) {
                int row = i * 16 + quad * 4 + r;
                float v = silu_f(acc[i][r] + bval);
                ushort_t h = f2bf(v);
                Hh[row * 136 + col] = h;
                Hl[row * 136 + col] = f2bf(v - bf2f(h));
            }
    }

    #pragma unroll
    for (int i = 0; i < 2; ++i)
        #pragma unroll
        for (int r = 0; r < 4; ++r) acc[i][r] = 0.f;
    loadB2(0); writeB(0);
    __syncthreads();
    #pragma unroll
    for (int it = 0; it < 12; ++it) {
        const int k0 = (it & 3) * 32;
        if (it + 1 < 12) loadB2(it + 1);
        bf16x8 ahf[2], alf[2], bhf, blf;
        #pragma unroll
        for (int i = 0; i < 2; ++i) {
            int ar = (i * 16 + row_l) * 136 + k0 + quad * 8;
            ahf[i] = *(const bf16x8*)&Hh[ar];
            alf[i] = *(const bf16x8*)&Hl[ar];
        }
        {
            int br = (wn16 + row_l) * 40 + quad * 8;
            bhf = *(const bf16x8*)&Bh[it & 1][br];
            blf = *(const bf16x8*)&Bl[it & 1][br];
        }
        #pragma unroll
        for (int i = 0; i < 2; ++i) {
            acc[i] = __builtin_amdgcn_mfma_f32_16x16x32_bf16(ahf[i], bhf, acc[i], 0, 0, 0);
            acc[i] = __builtin_amdgcn_mfma_f32_16x16x32_bf16(ahf[i], blf, acc[i], 0, 0, 0);
            acc[i] = __builtin_amdgcn_mfma_f32_16x16x32_bf16(alf[i], bhf, acc[i], 0, 0, 0);
        }
        if ((it & 3) == 3) {
            const int ct = it >> 2;
            int col = ct * 128 + wn16 + row_l;
            float bval = b2[col];
            #pragma unroll
            for (int i = 0; i < 2; ++i)
                #pragma unroll
                for (int r = 0; r < 4; ++r) {
                    int row = i * 16 + quad * 4 + r;
                    C[(size_t)(m0 + row) * 384 + col] = acc[i][r] + bval;
                }
            #pragma unroll
            for (int i = 0; i < 2; ++i)
                #pragma unroll
                for (int r = 0; r < 4; ++r) acc[i][r] = 0.f;
        }
        if (it + 1 < 12) writeB((it + 1) & 1);
        __syncthreads();
    }
}

// ---------------- fused update (+ next phi / readout tail), 512 threads / 8 waves ----------------
// (r13-verified) Same 32-atom tile & staged pipeline; each wave owns 16 output cols
// (32 in phase 0) so 2 waves/SIMD co-reside and hide latency. Bit-identical numerics.
template<int TAIL>
__global__ __launch_bounds__(512) void updphi_kernel(
    float* __restrict__ s_io, float* __restrict__ v_io,
    const ushort_t* __restrict__ UVh, const ushort_t* __restrict__ UVl,
    const ushort_t* __restrict__ W1h, const ushort_t* __restrict__ W1l,
    const float* __restrict__ b1,
    const ushort_t* __restrict__ W2h, const ushort_t* __restrict__ W2l,
    const float* __restrict__ b2,
    const ushort_t* __restrict__ XW1h, const ushort_t* __restrict__ XW1l,
    const float* __restrict__ xb1,
    const ushort_t* __restrict__ XW2h, const ushort_t* __restrict__ XW2l,
    const float* __restrict__ xb2,
    float* __restrict__ phi_out,
    const float* __restrict__ w2ro, const float* __restrict__ b2ro,
    const int* __restrict__ mol, float* __restrict__ outp)
{
    __shared__ float uvv[96][260];                     // [ln*3+d][0:128 uv | 128:256 vv]
    __shared__ __align__(16) ushort_t Bh[2][128 * 40];
    __shared__ __align__(16) ushort_t Bl[2][128 * 40];
    __shared__ __align__(16) unsigned char AH[17408];  // union: A-stage dbuf / H
    __shared__ float molacc[128];                      // TAIL=1 only
    __shared__ float redl[32][8];                      // TAIL=1 only
    const int tid = threadIdx.x;
    const int wave = tid >> 6, lane = tid & 63;        // wave 0..7
    const int row_l = lane & 15, quad = lane >> 4;
    const int wn16 = wave * 16;                        // phase 1/2/3 col base
    const int wn32 = wave * 32;                        // phase 0 col base
    const int m0 = blockIdx.x * 32;
    const int lrA = tid >> 3;          // 0..63 (A-stage helpers use tid<256 -> 0..31)
    const int ksA = (tid & 7) * 4;     // 0,4,..28
    const int lrB4 = tid >> 2, ksB4 = (tid & 3) * 8;   // B-stage (128 rows x 32k, 1 uint4/thr)

    float* sS = &uvv[0][0];            // 32 x 132 f32 (overlays dead uvv rows in phase 2 tail)
    constexpr int SSTR = 132;

    // ================= phase 0: [uv|vv] = v @ UVt (M=96, N=256, K=128) =================
    {
        ushort_t* A0h = (ushort_t*)AH;                 // [96][40]
        ushort_t* A0l = A0h + 96 * 40;
        ushort_t* B0h = &Bh[0][0];                     // [256][40] spans both buffers
        ushort_t* B0l = &Bl[0][0];
        f32x4 acc0[6][2];
        #pragma unroll
        for (int i = 0; i < 6; ++i)
            #pragma unroll
            for (int j = 0; j < 2; ++j)
                #pragma unroll
                for (int r = 0; r < 4; ++r) acc0[i][j][r] = 0.f;
        auto stageA0 = [&](int row, int k0) {
            float4 v = *(const float4*)&v_io[(size_t)(m0 * 3 + row) * 128 + k0 + ksA];
            float e[4] = {v.x, v.y, v.z, v.w};
            ushort_t ph[4], pl[4];
            #pragma unroll
            for (int t = 0; t < 4; ++t) {
                ushort_t h = f2bf(e[t]);
                ph[t] = h; pl[t] = f2bf(e[t] - bf2f(h));
            }
            *(uint2*)&A0h[row * 40 + ksA] = *(uint2*)ph;
            *(uint2*)&A0l[row * 40 + ksA] = *(uint2*)pl;
        };
        for (int k0 = 0; k0 < 128; k0 += 32) {
            stageA0(lrA, k0);                          // rows 0..63
            if (tid < 256) stageA0(64 + lrA, k0);      // rows 64..95
            {
                int row = tid >> 1, hb = (tid & 1) * 16;
                const ushort_t* bh = &UVh[(size_t)row * 128 + k0 + hb];
                const ushort_t* bl = &UVl[(size_t)row * 128 + k0 + hb];
                *(uint4*)&B0h[row * 40 + hb]     = *(const uint4*)bh;
                *(uint4*)&B0h[row * 40 + hb + 8] = *(const uint4*)(bh + 8);
                *(uint4*)&B0l[row * 40 + hb]     = *(const uint4*)bl;
                *(uint4*)&B0l[row * 40 + hb + 8] = *(const uint4*)(bl + 8);
            }
            __syncthreads();
            bf16x8 a0h[6], a0l[6], b0h[2], b0l[2];
            #pragma unroll
            for (int i = 0; i < 6; ++i) {
                int ar = (i * 16 + row_l) * 40 + quad * 8;
                a0h[i] = *(const bf16x8*)&A0h[ar];
                a0l[i] = *(const bf16x8*)&A0l[ar];
            }
            #pragma unroll
            for (int j = 0; j < 2; ++j) {
                int br = (wn32 + j * 16 + row_l) * 40 + quad * 8;
                b0h[j] = *(const bf16x8*)&B0h[br];
                b0l[j] = *(const bf16x8*)&B0l[br];
            }
            #pragma unroll
            for (int i = 0; i < 6; ++i)
                #pragma unroll
                for (int j = 0; j < 2; ++j) {
                    acc0[i][j] = __builtin_amdgcn_mfma_f32_16x16x32_bf16(a0h[i], b0h[j], acc0[i][j], 0, 0, 0);
                    acc0[i][j] = __builtin_amdgcn_mfma_f32_16x16x32_bf16(a0h[i], b0l[j], acc0[i][j], 0, 0, 0);
                    acc0[i][j] = __builtin_amdgcn_mfma_f32_16x16x32_bf16(a0l[i], b0h[j], acc0[i][j], 0, 0, 0);
                }
            __syncthreads();
        }
        #pragma unroll
        for (int i = 0; i < 6; ++i)
            #pragma unroll
            for (int j = 0; j < 2; ++j)
                #pragma unroll
                for (int r = 0; r < 4; ++r)
                    uvv[i * 16 + quad * 4 + r][wn32 + j * 16 + row_l] = acc0[i][j][r];
        __syncthreads();
    }

    // ================= phase 1: h = silu([s | norm(vv)] @ W1 + b1) =================
    ushort_t* Ah1 = (ushort_t*)AH;                     // [2][32*40]
    ushort_t* Al1 = Ah1 + 2 * 32 * 40;
    ushort_t* Hh  = (ushort_t*)AH;                     // [32][136]
    ushort_t* Hl  = Hh + 32 * 136;

    float4 rx;
    uint4 b_h0, b_l0;

    auto loadB1 = [&](int k0) {
        b_h0 = *(const uint4*)&W1h[(size_t)lrB4 * 256 + k0 + ksB4];
        b_l0 = *(const uint4*)&W1l[(size_t)lrB4 * 256 + k0 + ksB4];
    };
    auto writeB = [&](int buf) {
        *(uint4*)&Bh[buf][lrB4 * 40 + ksB4] = b_h0;
        *(uint4*)&Bl[buf][lrB4 * 40 + ksB4] = b_l0;
    };
    auto writeA1 = [&](int buf, int k0) {              // tid < 256 only
        float e[4];
        if (k0 < 128) {
            e[0] = rx.x; e[1] = rx.y; e[2] = rx.z; e[3] = rx.w;
        } else {
            int f = k0 + ksA;          // uvv col 128..255 (vv)
            #pragma unroll
            for (int t = 0; t < 4; ++t) {
                float x = uvv[lrA * 3 + 0][f + t];
                float y = uvv[lrA * 3 + 1][f + t];
                float z = uvv[lrA * 3 + 2][f + t];
                e[t] = sqrtf(x * x + y * y + z * z + 1e-15f);
            }
        }
        ushort_t ph[4], pl[4];
        #pragma unroll
        for (int t = 0; t < 4; ++t) {
            ushort_t h = f2bf(e[t]);
            ph[t] = h; pl[t] = f2bf(e[t] - bf2f(h));
        }
        *(uint2*)&Ah1[buf * 1280 + lrA * 40 + ksA] = *(uint2*)ph;
        *(uint2*)&Al1[buf * 1280 + lrA * 40 + ksA] = *(uint2*)pl;
    };

    f32x4 acc[2];
    #pragma unroll
    for (int i = 0; i < 2; ++i)
        #pragma unroll
        for (int r = 0; r < 4; ++r) acc[i][r] = 0.f;

    if (tid < 256) rx = *(const float4*)&s_io[(size_t)(m0 + lrA) * 128 + ksA];
    loadB1(0);
    if (tid < 256) writeA1(0, 0);
    writeB(0);
    __syncthreads();
    #pragma unroll
    for (int it = 0; it < 8; ++it) {
        const int k0n = (it + 1) * 32;
        if (it + 1 < 8) {
            if (tid < 256 && k0n < 128) rx = *(const float4*)&s_io[(size_t)(m0 + lrA) * 128 + k0n + ksA];
            loadB1(k0n);
        }
        bf16x8 ahf[2], alf[2], bhf, blf;
        #pragma unroll
        for (int i = 0; i < 2; ++i) {
            int ar = (it & 1) * 1280 + (i * 16 + row_l) * 40 + quad * 8;
            ahf[i] = *(const bf16x8*)&Ah1[ar];
            alf[i] = *(const bf16x8*)&Al1[ar];
        }
        {
            int br = (wn16 + row_l) * 40 + quad * 8;
            bhf = *(const bf16x8*)&Bh[it & 1][br];
            blf = *(const bf16x8*)&Bl[it & 1][br];
        }
        #pragma unroll
        for (int i = 0; i < 2; ++i) {
            acc[i] = __builtin_amdgcn_mfma_f32_16x16x32_bf16(ahf[i], bhf, acc[i], 0, 0, 0);
            acc[i] = __builtin_amdgcn_mfma_f32_16x16x32_bf16(ahf[i], blf, acc[i], 0, 0, 0);
            acc[i] = __builtin_amdgcn_mfma_f32_16x16x32_bf16(alf[i], bhf, acc[i], 0, 0, 0);
        }
        if (it + 1 < 8) { if (tid < 256) writeA1((it + 1) & 1, k0n); writeB((it + 1) & 1); }
        __syncthreads();
    }
    // epilogue 1 -> H
    {
        int col = wn16 + row_l;
        float bval = b1[col];
        #pragma unroll
        for (int i = 0; i < 2; ++i)
            #pragma unroll
            for (int r = 0; r < 4; ++r) {
                int row = i * 16 + quad * 4 + r;
                float v = silu_f(acc[i][r] + bval);
                ushort_t h = f2bf(v);
                Hh[row * 136 + col] = h;
                Hl[row * 136 + col] = f2bf(v - bf2f(h));
            }
    }

    // ================= phase 2: a = h @ W2 + b2, finupd folded into ct epilogues =================
    constexpr int CT0 = TAIL ? 1 : 0;          // TAIL=1: a_vv unused (v dead) -> skip ct0
    constexpr int NIT2 = (3 - CT0) * 4;
    auto loadB2 = [&](int it2) {
        int ct = CT0 + (it2 >> 2), k0 = (it2 & 3) * 32;
        b_h0 = *(const uint4*)&W2h[(size_t)(ct * 128 + lrB4) * 128 + k0 + ksB4];
        b_l0 = *(const uint4*)&W2l[(size_t)(ct * 128 + lrB4) * 128 + k0 + ksB4];
    };

    #pragma unroll
    for (int i = 0; i < 2; ++i)
        #pragma unroll
        for (int r = 0; r < 4; ++r) acc[i][r] = 0.f;
    f32x4 ssum[2];

    loadB2(0); writeB(0);
    __syncthreads();
    #pragma unroll
    for (int it = 0; it < NIT2; ++it) {
        const int k0 = (it & 3) * 32;
        if (it + 1 < NIT2) loadB2(it + 1);
        bf16x8 ahf[2], alf[2], bhf, blf;
        #pragma unroll
        for (int i = 0; i < 2; ++i) {
            int ar = (i * 16 + row_l) * 136 + k0 + quad * 8;
            ahf[i] = *(const bf16x8*)&Hh[ar];
            alf[i] = *(const bf16x8*)&Hl[ar];
        }
        {
            int br = (wn16 + row_l) * 40 + quad * 8;
            bhf = *(const bf16x8*)&Bh[it & 1][br];
            blf = *(const bf16x8*)&Bl[it & 1][br];
        }
        #pragma unroll
        for (int i = 0; i < 2; ++i) {
            acc[i] = __builtin_amdgcn_mfma_f32_16x16x32_bf16(ahf[i], bhf, acc[i], 0, 0, 0);
            acc[i] = __builtin_amdgcn_mfma_f32_16x16x32_bf16(ahf[i], blf, acc[i], 0, 0, 0);
            acc[i] = __builtin_amdgcn_mfma_f32_16x16x32_bf16(alf[i], bhf, acc[i], 0, 0, 0);
        }
        if ((it & 3) == 3) {                     // column-tile epilogue + finupd slice
            const int ct = CT0 + (it >> 2);
            int f = wn16 + row_l;
            float bval = b2[ct * 128 + f];
            #pragma unroll
            for (int i = 0; i < 2; ++i)
                #pragma unroll
                for (int r = 0; r < 4; ++r) {
                    int ln = i * 16 + quad * 4 + r;
                    float a = acc[i][r] + bval;
                    if (ct == 0) {                      // a_vv: v += uv * a
                        size_t vb = (size_t)(m0 + ln) * 3 * F + f;
                        v_io[vb]         += uvv[ln * 3 + 0][f] * a;
                        v_io[vb + F]     += uvv[ln * 3 + 1][f] * a;
                        v_io[vb + 2 * F] += uvv[ln * 3 + 2][f] * a;
                    } else if (ct == 1) {               // a_sv: ssum = <uv,vv> * a
                        float dot = uvv[ln * 3 + 0][f] * uvv[ln * 3 + 0][128 + f]
                                  + uvv[ln * 3 + 1][f] * uvv[ln * 3 + 1][128 + f]
                                  + uvv[ln * 3 + 2][f] * uvv[ln * 3 + 2][128 + f];
                        ssum[i][r] = dot * a;
                    } else {                            // a_ss: s_new = s + ssum + a
                        float sv = s_io[(size_t)(m0 + ln) * F + f] + ssum[i][r] + a;
                        if constexpr (TAIL == 0) s_io[(size_t)(m0 + ln) * F + f] = sv;
                        sS[ln * SSTR + f] = sv;         // sS overlays uvv rows (dead by now)
                    }
                }
            #pragma unroll
            for (int i = 0; i < 2; ++i)
                #pragma unroll
                for (int r = 0; r < 4; ++r) acc[i][r] = 0.f;
        }
        if (it + 1 < NIT2) writeB((it + 1) & 1);
        __syncthreads();
    }

    // ================= phase 3: next-phi MLP (TAIL=0) or readout (TAIL=1), A = sS =================
    if constexpr (TAIL == 1) { if (tid < 128) molacc[tid] = 0.f; }
    ushort_t* Ah3 = (ushort_t*)AH;
    ushort_t* Al3 = Ah3 + 2 * 1280;

    auto loadB31 = [&](int k0) {
        b_h0 = *(const uint4*)&XW1h[(size_t)lrB4 * 128 + k0 + ksB4];
        b_l0 = *(const uint4*)&XW1l[(size_t)lrB4 * 128 + k0 + ksB4];
    };
    auto writeA3 = [&](int buf, int k0) {              // tid < 256 only
        float e[4];
        #pragma unroll
        for (int t = 0; t < 4; ++t) e[t] = sS[lrA * SSTR + k0 + ksA + t];
        ushort_t ph[4], pl[4];
        #pragma unroll
        for (int t = 0; t < 4; ++t) {
            ushort_t h = f2bf(e[t]);
            ph[t] = h; pl[t] = f2bf(e[t] - bf2f(h));
        }
        *(uint2*)&Ah3[buf * 1280 + lrA * 40 + ksA] = *(uint2*)ph;
        *(uint2*)&Al3[buf * 1280 + lrA * 40 + ksA] = *(uint2*)pl;
    };

    #pragma unroll
    for (int i = 0; i < 2; ++i)
        #pragma unroll
        for (int r = 0; r < 4; ++r) acc[i][r] = 0.f;

    loadB31(0);
    if (tid < 256) writeA3(0, 0);
    writeB(0);
    __syncthreads();
    #pragma unroll
    for (int it = 0; it < 4; ++it) {
        const int k0n = (it + 1) * 32;
        if (it + 1 < 4) loadB31(k0n);
        bf16x8 ahf[2], alf[2], bhf, blf;
        #pragma unroll
        for (int i = 0; i < 2; ++i) {
            int ar = (it & 1) * 1280 + (i * 16 + row_l) * 40 + quad * 8;
            ahf[i] = *(const bf16x8*)&Ah3[ar];
            alf[i] = *(const bf16x8*)&Al3[ar];
        }
        {
            int br = (wn16 + row_l) * 40 + quad * 8;
            bhf = *(const bf16x8*)&Bh[it & 1][br];
            blf = *(const bf16x8*)&Bl[it & 1][br];
        }
        #pragma unroll
        for (int i = 0; i < 2; ++i) {
            acc[i] = __builtin_amdgcn_mfma_f32_16x16x32_bf16(ahf[i], bhf, acc[i], 0, 0, 0);
            acc[i] = __builtin_amdgcn_mfma_f32_16x16x32_bf16(ahf[i], blf, acc[i], 0, 0, 0);
            acc[i] = __builtin_amdgcn_mfma_f32_16x16x32_bf16(alf[i], bhf, acc[i], 0, 0, 0);
        }
        if (it + 1 < 4) { if (tid < 256) writeA3((it + 1) & 1, k0n); writeB((it + 1) & 1); }
        __syncthreads();
    }

    if constexpr (TAIL == 0) {
        // -> H, then stage 2 with XW2 -> phi_out
        {
            int col = wn16 + row_l;
            float bval = xb1[col];
            #pragma unroll
            for (int i = 0; i < 2; ++i)
                #pragma unroll
                for (int r = 0; r < 4; ++r) {
                    int row = i * 16 + quad * 4 + r;
                    float v = silu_f(acc[i][r] + bval);
                    ushort_t h = f2bf(v);
                    Hh[row * 136 + col] = h;
                    Hl[row * 136 + col] = f2bf(v - bf2f(h));
                }
        }
        auto loadB32 = [&](int it2) {
            int ct = it2 >> 2, k0 = (it2 & 3) * 32;
            b_h0 = *(const uint4*)&XW2h[(size_t)(ct * 128 + lrB4) * 128 + k0 + ksB4];
            b_l0 = *(const uint4*)&XW2l[(size_t)(ct * 128 + lrB4) * 128 + k0 + ksB4];
        };
        #pragma unroll
        for (int i = 0; i < 2; ++i)
            #pragma unroll
            for (int r = 0; r < 4; ++r) acc[i][r] = 0.f;
        loadB32(0); writeB(0);
        __syncthreads();
        #pragma unroll
        for (int it = 0; it < 12; ++it) {
            const int k0 = (it & 3) * 32;
            if (it + 1 < 12) loadB32(it + 1);
            bf16x8 ahf[2], alf[2], bhf, blf;
            #pragma unroll
            for (int i = 0; i < 2; ++i) {
                int ar = (i * 16 + row_l) * 136 + k0 + quad * 8;
                ahf[i] = *(const bf16x8*)&Hh[ar];
                alf[i] = *(const bf16x8*)&Hl[ar];
            }
            {
                int br = (wn16 + row_l) * 40 + quad * 8;
                bhf = *(const bf16x8*)&Bh[it & 1][br];
                blf = *(const bf16x8*)&Bl[it & 1][br];
            }
            #pragma unroll
            for (int i = 0; i < 2; ++i) {
                acc[i] = __builtin_amdgcn_mfma_f32_16x16x32_bf16(ahf[i], bhf, acc[i], 0, 0, 0);
                acc[i] = __builtin_amdgcn_mfma_f32_16x16x32_bf16(ahf[i], blf, acc[i], 0, 0, 0);
                acc[i] = __builtin_amdgcn_mfma_f32_16x16x32_bf16(alf[i], bhf, acc[i], 0, 0, 0);
            }
            if ((it & 3) == 3) {
                const int ct = it >> 2;
                int col = ct * 128 + wn16 + row_l;
                float bval = xb2[col];
                #pragma unroll
                for (int i = 0; i < 2; ++i)
                    #pragma unroll
                    for (int r = 0; r < 4; ++r) {
                        int row = i * 16 + quad * 4 + r;
                        phi_out[(size_t)(m0 + row) * 384 + col] = acc[i][r] + bval;
                    }
                #pragma unroll
                for (int i = 0; i < 2; ++i)
                    #pragma unroll
                    for (int r = 0; r < 4; ++r) acc[i][r] = 0.f;
            }
            if (it + 1 < 12) writeB((it + 1) & 1);
            __syncthreads();
        }
    } else {
        // readout: atom_e = sum_{col<64} silu(acc+robias)·w2 ; block mol table -> out
        float part[2][4];
        #pragma unroll
        for (int i = 0; i < 2; ++i)
            #pragma unroll
            for (int r = 0; r < 4; ++r) part[i][r] = 0.f;
        {
            int col = wn16 + row_l;
            float bv = xb1[col];                       // robias (zero-padded)
            float wv = (col < 64) ? w2ro[col] : 0.f;
            #pragma unroll
            for (int i = 0; i < 2; ++i)
                #pragma unroll
                for (int r = 0; r < 4; ++r)
                    part[i][r] += silu_f(acc[i][r] + bv) * wv;
        }
        #pragma unroll
        for (int o = 1; o < 16; o <<= 1)
            #pragma unroll
            for (int i = 0; i < 2; ++i)
                #pragma unroll
                for (int r = 0; r < 4; ++r)
                    part[i][r] += __shfl_xor(part[i][r], o);
        if (row_l == 0)
            #pragma unroll
            for (int i = 0; i < 2; ++i)
                #pragma unroll
                for (int r = 0; r < 4; ++r)
                    redl[i * 16 + quad * 4 + r][wave] = part[i][r];
        __syncthreads();
        if (tid < 32) {
            int n = m0 + tid;
            if (n < N_ATOMS) {
                float e = redl[tid][0] + redl[tid][1] + redl[tid][2] + redl[tid][3]
                        + redl[tid][4] + redl[tid][5] + redl[tid][6] + redl[tid][7] + b2ro[0];
                atomicAdd(&molacc[mol[n]], e);
            }
        }
        __syncthreads();
        if (tid < 100 && molacc[tid] != 0.f) atomicAdd(&outp[tid], molacc[tid]);
    }
}

// ---------------- atom-centric message gather (atomic-free, packed records) ----------------
template<int ZVIN>
__global__ __launch_bounds__(128) void msg_gather(
    const float* __restrict__ phi, const float* __restrict__ rec,
    const float* __restrict__ rbf_w, const float* __restrict__ rbf_b,
    const float* __restrict__ v_in, float* __restrict__ s,
    float* __restrict__ v_out, const int* __restrict__ offsets,
    const int* __restrict__ cnt)
{
    const int n = blockIdx.x, tid = threadIdx.x;
    float W0[N_RBF], W1[N_RBF], W2[N_RBF];
    #pragma unroll
    for (int k = 0; k < N_RBF; ++k) {
        W0[k] = rbf_w[k*3*F + tid];
        W1[k] = rbf_w[k*3*F + F + tid];
        W2[k] = rbf_w[k*3*F + 2*F + tid];
    }
    const float b0 = rbf_b[tid], b1 = rbf_b[F + tid], b2 = rbf_b[2*F + tid];
    float ds = 0.f, dvx = 0.f, dvy = 0.f, dvz = 0.f;
    const int off = offsets[n], c = cnt[n];
    const float* r = rec + (size_t)off * REC;
    #pragma unroll 2
    for (int t = 0; t < c; ++t, r += REC) {
        int j = __float_as_int(r[0]);
        float ev = r[1];
        float ux = r[2], uy = r[3], uz = r[4];
        float w0 = b0 * ev, w1 = b1 * ev, w2 = b2 * ev;
        #pragma unroll
        for (int k = 0; k < N_RBF; ++k) {
            float rk = r[5 + k];
            w0 += rk * W0[k]; w1 += rk * W1[k]; w2 += rk * W2[k];
        }
        const float* prow = phi + (size_t)j * 3 * F;
        float s0 = prow[tid] * w0;
        float s1 = prow[F + tid] * w1;
        float s2 = prow[2*F + tid] * w2;
        ds  += s1;
        if constexpr (ZVIN) {
            dvx += s2*ux; dvy += s2*uy; dvz += s2*uz;
        } else {
            const float* vrow = v_in + (size_t)j * 3 * F;
            dvx += s2*ux + s0 * vrow[tid];
            dvy += s2*uy + s0 * vrow[F + tid];
            dvz += s2*uz + s0 * vrow[2*F + tid];
        }
    }
    s[(size_t)n * F + tid] += ds;
    size_t vb = (size_t)n * 3 * F + tid;
    if constexpr (ZVIN) {
        v_out[vb]       = dvx;
        v_out[vb + F]   = dvy;
        v_out[vb + 2*F] = dvz;
    } else {
        v_out[vb]       = v_in[vb]       + dvx;
        v_out[vb + F]   = v_in[vb + F]   + dvy;
        v_out[vb + 2*F] = v_in[vb + 2*F] + dvz;
    }
}

extern "C" void kernel_launch(void* const* d_in, const int* in_sizes, int n_in,
                              void* d_out, int out_size, void* d_ws, size_t ws_size,
                              hipStream_t stream)
{
    const float* xyz    = (const float*)d_in[0];
    const float* emb    = (const float*)d_in[1];
    const float* msg_w1 = (const float*)d_in[2];
    const float* msg_b1 = (const float*)d_in[3];
    const float* msg_w2 = (const float*)d_in[4];
    const float* msg_b2 = (const float*)d_in[5];
    const float* rbf_w  = (const float*)d_in[6];
    const float* rbf_b  = (const float*)d_in[7];
    const float* upd_u  = (const float*)d_in[8];
    const float* upd_v  = (const float*)d_in[9];
    const float* upd_w1 = (const float*)d_in[10];
    const float* upd_b1 = (const float*)d_in[11];
    const float* upd_w2 = (const float*)d_in[12];
    const float* upd_b2 = (const float*)d_in[13];
    const float* ro_w1  = (const float*)d_in[14];
    const float* ro_b1  = (const float*)d_in[15];
    const float* ro_w2  = (const float*)d_in[16];
    const float* ro_b2  = (const float*)d_in[17];
    const int*   z      = (const int*)d_in[18];
    const int*   nbrs   = (const int*)d_in[19];
    const int*   molidx = (const int*)d_in[20];
    float* out = (float*)d_out;

    float* ws = (float*)d_ws;
    size_t off = 0;
    auto alloc = [&](size_t n) { float* p = ws + off; off += n; return p; };
    float* s_buf   = alloc(NFC);
    float* v1_buf  = alloc(3 * NFC);       // [n][3][f]
    float* v2_buf  = alloc(3 * NFC);
    float* phi_buf = alloc(3 * NFC);
    float* envb    = alloc(N_EDGES);
    float* edgerec = alloc((size_t)N_EDGES * REC);
    ushort_t* wbf_hi = (ushort_t*)alloc(WPREP_W / 2 + 64);
    ushort_t* wbf_lo = (ushort_t*)alloc(WPREP_W / 2 + 64);
    float* robias   = alloc(128);
    int* cnt        = (int*)alloc(N_ATOMS);
    int* cursor     = (int*)alloc(N_ATOMS);   // adjacent to cnt (zeroed together)
    int* offsets    = (int*)alloc(N_ATOMS);

    // bf16 weight sub-offsets (elements, see prep_kernel)
    const size_t oW1 = 0, oW2 = 49152, oUV = 196608, oU1 = 294912, oU2 = 393216, oRO = 540672;

    prep_kernel<<<dim3(PREP_TOTAL / 256), dim3(256), 0, stream>>>(
        emb, z, s_buf,
        msg_w1, msg_w2, upd_u, upd_v, upd_w1, upd_w2, ro_w1, ro_b1,
        wbf_hi, wbf_lo, robias, cnt);
    count_kernel<<<dim3((N_EDGES + 255) / 256), dim3(256), 0, stream>>>(
        xyz, nbrs, envb, cnt);
    scan_kernel<<<dim3(1), dim3(1024), 0, stream>>>(cnt, offsets, out);
    // merged (512 thr): phi_0 MLP 8-wave (blocks [0,252)) + build (blocks [252,565))
    build_phi0_kernel<<<dim3(NPHI_BLK + NBUILD_BLK), dim3(512), 0, stream>>>(
        xyz, nbrs, envb, offsets, cursor, edgerec,
        s_buf,
        wbf_hi + oW1, wbf_lo + oW1, msg_b1,
        wbf_hi + oW2, wbf_lo + oW2, msg_b2,
        phi_buf);

    float* vin = v1_buf;
    float* vout = v2_buf;
    for (int i = 0; i < 3; ++i) {
        if (i == 0)
            msg_gather<1><<<dim3(N_ATOMS), dim3(128), 0, stream>>>(
                phi_buf, edgerec, rbf_w + (size_t)i*N_RBF*3*F, rbf_b + (size_t)i*3*F,
                vin, s_buf, vout, offsets, cnt);
        else
            msg_gather<0><<<dim3(N_ATOMS), dim3(128), 0, stream>>>(
                phi_buf, edgerec, rbf_w + (size_t)i*N_RBF*3*F, rbf_b + (size_t)i*3*F,
                vin, s_buf, vout, offsets, cnt);
        if (i < 2) {
            // upd(i) + phi(i+1) fused (512 threads / 8 waves)
            updphi_kernel<0><<<dim3(NP/32), dim3(512), 0, stream>>>(
                s_buf, vout,
                wbf_hi + oUV + (size_t)i*32768, wbf_lo + oUV + (size_t)i*32768,
                wbf_hi + oU1 + (size_t)i*32768, wbf_lo + oU1 + (size_t)i*32768,
                upd_b1 + (size_t)i*F,
                wbf_hi + oU2 + (size_t)i*49152, wbf_lo + oU2 + (size_t)i*49152,
                upd_b2 + (size_t)i*3*F,
                wbf_hi + oW1 + (size_t)(i+1)*16384, wbf_lo + oW1 + (size_t)(i+1)*16384,
                msg_b1 + (size_t)(i+1)*F,
                wbf_hi + oW2 + (size_t)(i+1)*49152, wbf_lo + oW2 + (size_t)(i+1)*49152,
                msg_b2 + (size_t)(i+1)*3*F,
                phi_buf,
                nullptr, nullptr, nullptr, nullptr);
        } else {
            // upd(2) + readout + mol reduce fused
            updphi_kernel<1><<<dim3(NP/32), dim3(512), 0, stream>>>(
                s_buf, vout,
                wbf_hi + oUV + (size_t)i*32768, wbf_lo + oUV + (size_t)i*32768,
                wbf_hi + oU1 + (size_t)i*32768, wbf_lo + oU1 + (size_t)i*32768,
                upd_b1 + (size_t)i*F,
                wbf_hi + oU2 + (size_t)i*49152, wbf_lo + oU2 + (size_t)i*49152,
                upd_b2 + (size_t)i*3*F,
                wbf_hi + oRO, wbf_lo + oRO, robias,
                nullptr, nullptr, nullptr,
                nullptr,
                ro_w2, ro_b2, molidx, out);
        }
        float* tmp = vin; vin = vout; vout = tmp;
    }
}